// Round 6
// baseline (399.315 us; speedup 1.0000x reference)
//
#include <hip/hip_runtime.h>

#define NTOK 197
#define NH 12
#define HD 64
#define DIMC 768
#define BATCH 64
#define ROWS (BATCH*NTOK)   // 12608
#define NPAD 224            // padded token count for Vt / P (7*32)
#define BHN (BATCH*NH)      // 768

typedef float f4 __attribute__((ext_vector_type(4)));
typedef __bf16 b8 __attribute__((ext_vector_type(8)));
typedef unsigned short u16x8 __attribute__((ext_vector_type(8)));
typedef unsigned short u16x4 __attribute__((ext_vector_type(4)));

__device__ inline unsigned short f2bf(float f) {
  unsigned u = __builtin_bit_cast(unsigned, f);
  u += 0x7fffu + ((u >> 16) & 1u);
  return (unsigned short)(u >> 16);
}

__device__ inline b8 ld8(const unsigned short* p) {
  return __builtin_bit_cast(b8, *(const u16x8*)p);
}

__device__ inline f4 mfma_bf16(b8 a, b8 b, f4 c) {
  return __builtin_amdgcn_mfma_f32_16x16x32_bf16(a, b, c, 0, 0, 0);
}

// ---------------- prep kernels ----------------

__global__ void k_cvt(const float* __restrict__ s, unsigned short* __restrict__ d, int n4) {
  int i = blockIdx.x * 256 + threadIdx.x;
  if (i < n4) {
    f4 v = *(const f4*)&s[(size_t)i * 4];
    u16x4 o = { f2bf(v[0]), f2bf(v[1]), f2bf(v[2]), f2bf(v[3]) };
    *(u16x4*)&d[(size_t)i * 4] = o;
  }
}

__global__ void k_bias(const float* __restrict__ table, const int* __restrict__ idx,
                       float* __restrict__ Bias) {
  int i = blockIdx.x * 256 + threadIdx.x;
  if (i < NH * NTOK * NTOK) {
    int h = i / (NTOK * NTOK);
    int nm = i - h * (NTOK * NTOK);
    Bias[i] = table[idx[nm] * NH + h];
  }
}

__global__ void k_vtpad(unsigned short* __restrict__ Vt) {
  int i = blockIdx.x * 256 + threadIdx.x;   // BHN*HD rows, pad cols 197..223
  const int PADW = NPAD - NTOK;             // 27
  if (i < BHN * HD * PADW) {
    int row = i / PADW, c = i - row * PADW;
    Vt[(size_t)row * NPAD + NTOK + c] = 0;
  }
}

// ---------------- direct-global MFMA GEMM: no LDS, no barriers ----------------
// A[M][768] bf16 row-major, Bm[N][768] bf16 row-major (= B^T).
// Working set is L2/L3-resident, so LDS staging only adds barrier convoys.
// 4 waves (2Mx2N), wave tile 64x128 (acc[4][8]); block tile 128x256.
// Per K-step(32): 4 A-frag + 8 B-frag 16B loads (each = 16 rows x 64B full lines),
// 32 MFMA. K fully unrolled (24 steps), 1-step register prefetch, all K-offsets
// fold into load immediates (kt*64B < 4096).
// MODE 0: qkv epilogue -> Q,K,Vt scatter.  MODE 1: proj epilogue -> fp32 out + bias.

template<int MODE>
__global__ __launch_bounds__(256, 2) void k_gemm(
    const unsigned short* __restrict__ A, const unsigned short* __restrict__ Bm,
    const float* __restrict__ bias0, const float* __restrict__ bias1,
    unsigned short* __restrict__ Qo, unsigned short* __restrict__ Ko,
    unsigned short* __restrict__ Vto, float* __restrict__ Co)
{
  const int NWG  = (MODE == 0) ? 891 : 297;   // 99 M-tiles(128) x {9|3} N-tiles(256)
  const int NROW = 99;

  int tid = threadIdx.x;
  int l = tid & 63, w = tid >> 6;         // 4 waves, 2Mx2N
  int lr = l & 15, lg = l >> 4;
  int wr = w >> 1, wc = w & 1;

  // bijective XCD swizzle (m204); consecutive s = same N-col stripe (B-panel reuse in XCD L2)
  int orig = blockIdx.x;
  const int q = NWG >> 3, rmod = NWG & 7;
  int xcd = orig & 7, loc = orig >> 3;
  int s = (xcd < rmod ? xcd * (q + 1) : rmod * (q + 1) + (xcd - rmod) * q) + loc;
  int brow = (s % NROW) * 128;
  int bcol = (s / NROW) * 256;

  // 32-bit element offsets (saddr + voffset form; kt*32 folds into offset imm)
  unsigned oA[4], oB[8];
  #pragma unroll
  for (int mi = 0; mi < 4; mi++) {
    int ar = brow + wr * 64 + mi * 16 + lr; if (ar > ROWS - 1) ar = ROWS - 1;
    oA[mi] = (unsigned)ar * DIMC + lg * 8;
  }
  #pragma unroll
  for (int ni = 0; ni < 8; ni++) {
    int br = bcol + wc * 128 + ni * 16 + lr;
    oB[ni] = (unsigned)br * DIMC + lg * 8;
  }

  f4 acc[4][8];
  #pragma unroll
  for (int i = 0; i < 4; i++)
    #pragma unroll
    for (int j = 0; j < 8; j++) acc[i][j] = (f4){0.f, 0.f, 0.f, 0.f};

  b8 aX[4], bX[8], aY[4], bY[8];
  #pragma unroll
  for (int mi = 0; mi < 4; mi++) aX[mi] = ld8(A + oA[mi]);
  #pragma unroll
  for (int ni = 0; ni < 8; ni++) bX[ni] = ld8(Bm + oB[ni]);

  #pragma unroll
  for (int kt = 0; kt < 24; kt += 2) {
    // prefetch kt+1 while computing kt
    #pragma unroll
    for (int mi = 0; mi < 4; mi++) aY[mi] = ld8(A + oA[mi] + (kt + 1) * 32);
    #pragma unroll
    for (int ni = 0; ni < 8; ni++) bY[ni] = ld8(Bm + oB[ni] + (kt + 1) * 32);
    #pragma unroll
    for (int mi = 0; mi < 4; mi++)
      #pragma unroll
      for (int ni = 0; ni < 8; ni++)
        acc[mi][ni] = mfma_bf16(aX[mi], bX[ni], acc[mi][ni]);
    // prefetch kt+2 while computing kt+1
    if (kt + 2 < 24) {
      #pragma unroll
      for (int mi = 0; mi < 4; mi++) aX[mi] = ld8(A + oA[mi] + (kt + 2) * 32);
      #pragma unroll
      for (int ni = 0; ni < 8; ni++) bX[ni] = ld8(Bm + oB[ni] + (kt + 2) * 32);
    }
    #pragma unroll
    for (int mi = 0; mi < 4; mi++)
      #pragma unroll
      for (int ni = 0; ni < 8; ni++)
        acc[mi][ni] = mfma_bf16(aY[mi], bY[ni], acc[mi][ni]);
  }

  // ---- epilogue ----
  #pragma unroll
  for (int mi = 0; mi < 4; mi++) {
    #pragma unroll
    for (int ni = 0; ni < 8; ni++) {
      #pragma unroll
      for (int r = 0; r < 4; r++) {
        int rg = brow + wr * 64 + mi * 16 + lg * 4 + r;
        int cg = bcol + wc * 128 + ni * 16 + lr;
        if (rg < ROWS) {
          float v = acc[mi][ni][r];
          if (MODE == 0) {
            int which = cg / DIMC;        // 0=q 1=k 2=v
            int rem = cg - which * DIMC;
            int h = rem >> 6, d = rem & 63;
            int b = rg / NTOK, n = rg - (rg / NTOK) * NTOK;
            int bh = b * NH + h;
            if (which == 0)      Qo[((size_t)bh * NTOK + n) * HD + d] = f2bf((v + bias0[rem]) * 0.125f);
            else if (which == 1) Ko[((size_t)bh * NTOK + n) * HD + d] = f2bf(v);
            else                 Vto[((size_t)bh * HD + d) * NPAD + n] = f2bf(v + bias1[rem]);
          } else {
            Co[(size_t)rg * DIMC + cg] = v + bias0[cg];
          }
        }
      }
    }
  }
}

// ---------------- fused attention: 1 block per (b,h), 4 waves ----------------

__global__ __launch_bounds__(256) void k_attn(
    const unsigned short* __restrict__ Q, const unsigned short* __restrict__ Kb,
    const unsigned short* __restrict__ Vt, const float* __restrict__ Bias,
    unsigned short* __restrict__ Abuf)
{
  int bh = blockIdx.x;
  int b = bh / NH, h = bh - (bh / NH) * NH;
  const unsigned short* q  = Q  + (size_t)bh * NTOK * HD;
  const unsigned short* kk = Kb + (size_t)bh * NTOK * HD;
  const unsigned short* vt = Vt + (size_t)bh * HD * NPAD;
  const float* bias = Bias + (size_t)h * NTOK * NTOK;

  __shared__ unsigned short P[4][16 * NPAD];

  int tid = threadIdx.x, w = tid >> 6, l = tid & 63;
  int lr = l & 15, lg = l >> 4;

  for (int mt = w; mt < 13; mt += 4) {
    int qrow = mt * 16 + lr; if (qrow > NTOK - 1) qrow = NTOK - 1;
    b8 qa0 = ld8(&q[qrow * HD + lg * 8]);
    b8 qa1 = ld8(&q[qrow * HD + 32 + lg * 8]);

    f4 s[13];
    #pragma unroll
    for (int jt = 0; jt < 13; jt++) {
      int krow = jt * 16 + lr; if (krow > NTOK - 1) krow = NTOK - 1;
      b8 kb0 = ld8(&kk[krow * HD + lg * 8]);
      b8 kb1 = ld8(&kk[krow * HD + 32 + lg * 8]);
      f4 a = (f4){0.f, 0.f, 0.f, 0.f};
      a = mfma_bf16(qa0, kb0, a);
      a = mfma_bf16(qa1, kb1, a);
      s[jt] = a;
    }

    #pragma unroll
    for (int r = 0; r < 4; r++) {
      int n = mt * 16 + 4 * lg + r;
      int nc = n > NTOK - 1 ? NTOK - 1 : n;
      float rm = -1e30f;
      #pragma unroll
      for (int jt = 0; jt < 13; jt++) {
        int m = jt * 16 + lr;
        float v = s[jt][r];
        v = (m < NTOK) ? (v + bias[nc * NTOK + m]) : -1e30f;
        s[jt][r] = v;
        rm = fmaxf(rm, v);
      }
      rm = fmaxf(rm, __shfl_xor(rm, 1));
      rm = fmaxf(rm, __shfl_xor(rm, 2));
      rm = fmaxf(rm, __shfl_xor(rm, 4));
      rm = fmaxf(rm, __shfl_xor(rm, 8));
      float sum = 0.f;
      #pragma unroll
      for (int jt = 0; jt < 13; jt++) {
        float p = __expf(s[jt][r] - rm);
        s[jt][r] = p;
        sum += p;
      }
      sum += __shfl_xor(sum, 1);
      sum += __shfl_xor(sum, 2);
      sum += __shfl_xor(sum, 4);
      sum += __shfl_xor(sum, 8);
      float inv = 1.0f / sum;
      #pragma unroll
      for (int jt = 0; jt < 13; jt++)
        P[w][(4 * lg + r) * NPAD + jt * 16 + lr] = f2bf(s[jt][r] * inv);
    }
    #pragma unroll
    for (int e = 0; e < 4; e++) P[w][lr * NPAD + 208 + lg * 4 + e] = 0;

    __builtin_amdgcn_wave_barrier();

    #pragma unroll
    for (int dt = 0; dt < 4; dt++) {
      f4 o = (f4){0.f, 0.f, 0.f, 0.f};
      #pragma unroll
      for (int ktk = 0; ktk < 7; ktk++) {
        b8 pa = ld8(&P[w][lr * NPAD + ktk * 32 + lg * 8]);
        b8 vb = ld8(&vt[(dt * 16 + lr) * NPAD + ktk * 32 + lg * 8]);
        o = mfma_bf16(pa, vb, o);
      }
      #pragma unroll
      for (int r = 0; r < 4; r++) {
        int n = mt * 16 + 4 * lg + r;
        if (n < NTOK)
          Abuf[((size_t)b * NTOK + n) * DIMC + h * HD + dt * 16 + lr] = f2bf(o[r]);
      }
    }
  }
}

// ---------------- launch ----------------

extern "C" void kernel_launch(void* const* d_in, const int* in_sizes, int n_in,
                              void* d_out, int out_size, void* d_ws, size_t ws_size,
                              hipStream_t stream) {
  const float* x      = (const float*)d_in[0];
  const float* qkv_w  = (const float*)d_in[1];
  const float* q_bias = (const float*)d_in[2];
  const float* v_bias = (const float*)d_in[3];
  const float* rtab   = (const float*)d_in[4];
  const float* proj_w = (const float*)d_in[5];
  const float* proj_b = (const float*)d_in[6];
  const int*   ridx   = (const int*)d_in[7];
  float* out = (float*)d_out;

  char* p = (char*)d_ws;
  auto carve = [&](size_t bytes) { char* r = p; p += (bytes + 255) & ~(size_t)255; return r; };
  unsigned short* xb   = (unsigned short*)carve((size_t)ROWS * DIMC * 2);
  unsigned short* wb   = (unsigned short*)carve((size_t)3 * DIMC * DIMC * 2);
  unsigned short* pb   = (unsigned short*)carve((size_t)DIMC * DIMC * 2);
  float*          Bias = (float*)carve((size_t)NH * NTOK * NTOK * 4);
  unsigned short* Q    = (unsigned short*)carve((size_t)BHN * NTOK * HD * 2);
  unsigned short* Kb   = (unsigned short*)carve((size_t)BHN * NTOK * HD * 2);
  unsigned short* Vt   = (unsigned short*)carve((size_t)BHN * HD * NPAD * 2);
  unsigned short* Abuf = xb;  // xb is dead after GEMM1; attn fully overwrites

  k_cvt<<<(ROWS * DIMC / 4 + 255) / 256, 256, 0, stream>>>(x, xb, ROWS * DIMC / 4);
  k_cvt<<<(3 * DIMC * DIMC / 4 + 255) / 256, 256, 0, stream>>>(qkv_w, wb, 3 * DIMC * DIMC / 4);
  k_cvt<<<(DIMC * DIMC / 4 + 255) / 256, 256, 0, stream>>>(proj_w, pb, DIMC * DIMC / 4);
  k_bias<<<(NH * NTOK * NTOK + 255) / 256, 256, 0, stream>>>(rtab, ridx, Bias);
  k_vtpad<<<(BHN * HD * (NPAD - NTOK) + 255) / 256, 256, 0, stream>>>(Vt);

  k_gemm<0><<<891, 256, 0, stream>>>(xb, wb, q_bias, v_bias, Q, Kb, Vt, nullptr);

  k_attn<<<BHN, 256, 0, stream>>>(Q, Kb, Vt, Bias, Abuf);

  k_gemm<1><<<297, 256, 0, stream>>>(Abuf, pb, proj_b, nullptr, nullptr, nullptr, nullptr, out);
}

// Round 7
// 272.723 us; speedup vs baseline: 1.4642x; 1.4642x over previous
//
#include <hip/hip_runtime.h>

#define NTOK 197
#define NH 12
#define HD 64
#define DIMC 768
#define BATCH 64
#define ROWS (BATCH*NTOK)   // 12608
#define NPAD 224            // padded token count for Vt / P (7*32)
#define BHN (BATCH*NH)      // 768
#define KT 24               // K-tiles of 32

typedef float f4 __attribute__((ext_vector_type(4)));
typedef __bf16 b8 __attribute__((ext_vector_type(8)));
typedef unsigned short u16x8 __attribute__((ext_vector_type(8)));
typedef unsigned short u16x4 __attribute__((ext_vector_type(4)));

__device__ inline unsigned short f2bf(float f) {
  unsigned u = __builtin_bit_cast(unsigned, f);
  u += 0x7fffu + ((u >> 16) & 1u);
  return (unsigned short)(u >> 16);
}

__device__ inline b8 ld8(const unsigned short* p) {
  return __builtin_bit_cast(b8, *(const u16x8*)p);
}

__device__ inline f4 mfma_bf16(b8 a, b8 b, f4 c) {
  return __builtin_amdgcn_mfma_f32_16x16x32_bf16(a, b, c, 0, 0, 0);
}

// async global->LDS, 16B per lane, LDS dest = wave-uniform base + lane*16
__device__ inline void gload_lds16(const unsigned short* g, unsigned short* l) {
  __builtin_amdgcn_global_load_lds(
      (const __attribute__((address_space(1))) unsigned int*)g,
      (__attribute__((address_space(3))) unsigned int*)l, 16, 0, 0);
}

// ---------------- prep kernels ----------------

__global__ void k_cvt(const float* __restrict__ s, unsigned short* __restrict__ d, int n4) {
  int i = blockIdx.x * 256 + threadIdx.x;
  if (i < n4) {
    f4 v = *(const f4*)&s[(size_t)i * 4];
    u16x4 o = { f2bf(v[0]), f2bf(v[1]), f2bf(v[2]), f2bf(v[3]) };
    *(u16x4*)&d[(size_t)i * 4] = o;
  }
}

__global__ void k_bias(const float* __restrict__ table, const int* __restrict__ idx,
                       float* __restrict__ Bias) {
  int i = blockIdx.x * 256 + threadIdx.x;
  if (i < NH * NTOK * NTOK) {
    int h = i / (NTOK * NTOK);
    int nm = i - h * (NTOK * NTOK);
    Bias[i] = table[idx[nm] * NH + h];
  }
}

__global__ void k_vtpad(unsigned short* __restrict__ Vt) {
  int i = blockIdx.x * 256 + threadIdx.x;   // BHN*HD rows, pad cols 197..223
  const int PADW = NPAD - NTOK;             // 27
  if (i < BHN * HD * PADW) {
    int row = i / PADW, c = i - row * PADW;
    Vt[(size_t)row * NPAD + NTOK + c] = 0;
  }
}

// ---------------- 128x128 GEMM, T3 minimum-2-phase ----------------
// A[M][768] bf16 row-major, Bm[N][768] bf16 row-major (= B^T).
// 4 waves (2Mx2N), per-wave 64x64, BK=32, double-buffered 32KB LDS.
// Loop: STAGE(t+1 -> buf^1) BEFORE ds_read(buf)+MFMA, ONE __syncthreads
// per iter AFTER MFMA (drains own async stores; fences buffer swap).
// Granule-XOR swizzle (R3's, measured 0 conflicts): LDS[r][c] = glob[r][c^((r>>1)&3)]
// via pre-swizzled source; reads use c = lg ^ ((lr>>1)&3).
// MODE 0: qkv epilogue -> Q,K,Vt scatter.  MODE 1: proj epilogue -> fp32 out + bias.

template<int MODE>
__global__ __launch_bounds__(256, 3) void k_gemm(
    const unsigned short* __restrict__ A, const unsigned short* __restrict__ Bm,
    const float* __restrict__ bias0, const float* __restrict__ bias1,
    unsigned short* __restrict__ Qo, unsigned short* __restrict__ Ko,
    unsigned short* __restrict__ Vto, float* __restrict__ Co)
{
  __shared__ unsigned short As[2][128 * 32];
  __shared__ unsigned short Bs[2][128 * 32];

  const int NWG  = (MODE == 0) ? 1782 : 594;  // 99 x {18|6} tiles of 128
  const int NROW = 99;

  int tid = threadIdx.x;
  int l = tid & 63, w = tid >> 6;         // 4 waves
  int lr = l & 15, lg = l >> 4;
  int wr = w >> 1, wc = w & 1;

  // bijective XCD swizzle (m204)
  int orig = blockIdx.x;
  const int q = NWG >> 3, rmod = NWG & 7;
  int xcd = orig & 7, loc = orig >> 3;
  int s = (xcd < rmod ? xcd * (q + 1) : rmod * (q + 1) + (xcd - rmod) * q) + loc;
  int brow = (s % NROW) * 128;
  int bcol = (s / NROW) * 128;

  // ---- staging: 2 A-issues + 2 B-issues per wave, each 16 rows x 32 cols ----
  int srow = l >> 2;                                  // 0..15
  int scol = (((l & 3) ^ ((l >> 3) & 3)) * 8);        // pre-swizzled source col

  const unsigned short* pa[2]; const unsigned short* pb[2];
  int dst[2];
  #pragma unroll
  for (int j = 0; j < 2; j++) {
    int ar = brow + w * 32 + j * 16 + srow; if (ar > ROWS - 1) ar = ROWS - 1;
    int br = bcol + w * 32 + j * 16 + srow;
    pa[j] = A  + (size_t)ar * DIMC + scol;
    pb[j] = Bm + (size_t)br * DIMC + scol;
    dst[j] = (w * 32 + j * 16) * 32;
  }

  // ---- fragment read (swizzled col) ----
  int swzc = ((lg ^ ((lr >> 1) & 3)) * 8);
  int arow0 = wr * 64 + lr;
  int brow0 = wc * 64 + lr;

  f4 acc[4][4];
  #pragma unroll
  for (int i = 0; i < 4; i++)
    #pragma unroll
    for (int j = 0; j < 4; j++) acc[i][j] = (f4){0.f, 0.f, 0.f, 0.f};

  // prologue: stage tile 0 into buf 0
  #pragma unroll
  for (int j = 0; j < 2; j++) {
    gload_lds16(pa[j], &As[0][dst[j]]);
    gload_lds16(pb[j], &Bs[0][dst[j]]);
  }
  __syncthreads();

  for (int g = 0; g < KT; ++g) {
    int cur = g & 1, nxt = cur ^ 1;
    // phase 1: issue next tile's loads (async) into the other buffer
    if (g + 1 < KT) {
      #pragma unroll
      for (int j = 0; j < 2; j++) {
        gload_lds16(pa[j] + (g + 1) * 32, &As[nxt][dst[j]]);
        gload_lds16(pb[j] + (g + 1) * 32, &Bs[nxt][dst[j]]);
      }
    }
    // phase 2: compute current tile (compiler inserts lgkmcnt waits)
    b8 af[4], bf[4];
    #pragma unroll
    for (int mi = 0; mi < 4; mi++) af[mi] = ld8(&As[cur][(arow0 + mi * 16) * 32 + swzc]);
    #pragma unroll
    for (int ni = 0; ni < 4; ni++) bf[ni] = ld8(&Bs[cur][(brow0 + ni * 16) * 32 + swzc]);
    #pragma unroll
    for (int mi = 0; mi < 4; mi++)
      #pragma unroll
      for (int ni = 0; ni < 4; ni++)
        acc[mi][ni] = mfma_bf16(af[mi], bf[ni], acc[mi][ni]);
    // one barrier per iter: drains own vmcnt (stage complete) + fences swap
    __syncthreads();
  }

  // ---- epilogue ----
  #pragma unroll
  for (int mi = 0; mi < 4; mi++) {
    #pragma unroll
    for (int ni = 0; ni < 4; ni++) {
      #pragma unroll
      for (int r = 0; r < 4; r++) {
        int rg = brow + wr * 64 + mi * 16 + lg * 4 + r;
        int cg = bcol + wc * 64 + ni * 16 + lr;
        if (rg < ROWS) {
          float v = acc[mi][ni][r];
          if (MODE == 0) {
            int which = cg / DIMC;        // 0=q 1=k 2=v
            int rem = cg - which * DIMC;
            int h = rem >> 6, d = rem & 63;
            int b = rg / NTOK, n = rg - (rg / NTOK) * NTOK;
            int bh = b * NH + h;
            if (which == 0)      Qo[((size_t)bh * NTOK + n) * HD + d] = f2bf((v + bias0[rem]) * 0.125f);
            else if (which == 1) Ko[((size_t)bh * NTOK + n) * HD + d] = f2bf(v);
            else                 Vto[((size_t)bh * HD + d) * NPAD + n] = f2bf(v + bias1[rem]);
          } else {
            Co[(size_t)rg * DIMC + cg] = v + bias0[cg];
          }
        }
      }
    }
  }
}

// ---------------- fused attention: 1 block per (b,h), 4 waves ----------------

__global__ __launch_bounds__(256) void k_attn(
    const unsigned short* __restrict__ Q, const unsigned short* __restrict__ Kb,
    const unsigned short* __restrict__ Vt, const float* __restrict__ Bias,
    unsigned short* __restrict__ Abuf)
{
  int bh = blockIdx.x;
  int b = bh / NH, h = bh - (bh / NH) * NH;
  const unsigned short* q  = Q  + (size_t)bh * NTOK * HD;
  const unsigned short* kk = Kb + (size_t)bh * NTOK * HD;
  const unsigned short* vt = Vt + (size_t)bh * HD * NPAD;
  const float* bias = Bias + (size_t)h * NTOK * NTOK;

  __shared__ unsigned short P[4][16 * NPAD];

  int tid = threadIdx.x, w = tid >> 6, l = tid & 63;
  int lr = l & 15, lg = l >> 4;

  for (int mt = w; mt < 13; mt += 4) {
    int qrow = mt * 16 + lr; if (qrow > NTOK - 1) qrow = NTOK - 1;
    b8 qa0 = ld8(&q[qrow * HD + lg * 8]);
    b8 qa1 = ld8(&q[qrow * HD + 32 + lg * 8]);

    f4 s[13];
    #pragma unroll
    for (int jt = 0; jt < 13; jt++) {
      int krow = jt * 16 + lr; if (krow > NTOK - 1) krow = NTOK - 1;
      b8 kb0 = ld8(&kk[krow * HD + lg * 8]);
      b8 kb1 = ld8(&kk[krow * HD + 32 + lg * 8]);
      f4 a = (f4){0.f, 0.f, 0.f, 0.f};
      a = mfma_bf16(qa0, kb0, a);
      a = mfma_bf16(qa1, kb1, a);
      s[jt] = a;
    }

    #pragma unroll
    for (int r = 0; r < 4; r++) {
      int n = mt * 16 + 4 * lg + r;
      int nc = n > NTOK - 1 ? NTOK - 1 : n;
      float rm = -1e30f;
      #pragma unroll
      for (int jt = 0; jt < 13; jt++) {
        int m = jt * 16 + lr;
        float v = s[jt][r];
        v = (m < NTOK) ? (v + bias[nc * NTOK + m]) : -1e30f;
        s[jt][r] = v;
        rm = fmaxf(rm, v);
      }
      rm = fmaxf(rm, __shfl_xor(rm, 1));
      rm = fmaxf(rm, __shfl_xor(rm, 2));
      rm = fmaxf(rm, __shfl_xor(rm, 4));
      rm = fmaxf(rm, __shfl_xor(rm, 8));
      float sum = 0.f;
      #pragma unroll
      for (int jt = 0; jt < 13; jt++) {
        float p = __expf(s[jt][r] - rm);
        s[jt][r] = p;
        sum += p;
      }
      sum += __shfl_xor(sum, 1);
      sum += __shfl_xor(sum, 2);
      sum += __shfl_xor(sum, 4);
      sum += __shfl_xor(sum, 8);
      float inv = 1.0f / sum;
      #pragma unroll
      for (int jt = 0; jt < 13; jt++)
        P[w][(4 * lg + r) * NPAD + jt * 16 + lr] = f2bf(s[jt][r] * inv);
    }
    #pragma unroll
    for (int e = 0; e < 4; e++) P[w][lr * NPAD + 208 + lg * 4 + e] = 0;

    __builtin_amdgcn_wave_barrier();

    #pragma unroll
    for (int dt = 0; dt < 4; dt++) {
      f4 o = (f4){0.f, 0.f, 0.f, 0.f};
      #pragma unroll
      for (int ktk = 0; ktk < 7; ktk++) {
        b8 pa = ld8(&P[w][lr * NPAD + ktk * 32 + lg * 8]);
        b8 vb = ld8(&vt[(dt * 16 + lr) * NPAD + ktk * 32 + lg * 8]);
        o = mfma_bf16(pa, vb, o);
      }
      #pragma unroll
      for (int r = 0; r < 4; r++) {
        int n = mt * 16 + 4 * lg + r;
        if (n < NTOK)
          Abuf[((size_t)b * NTOK + n) * DIMC + h * HD + dt * 16 + lr] = f2bf(o[r]);
      }
    }
  }
}

// ---------------- launch ----------------

extern "C" void kernel_launch(void* const* d_in, const int* in_sizes, int n_in,
                              void* d_out, int out_size, void* d_ws, size_t ws_size,
                              hipStream_t stream) {
  const float* x      = (const float*)d_in[0];
  const float* qkv_w  = (const float*)d_in[1];
  const float* q_bias = (const float*)d_in[2];
  const float* v_bias = (const float*)d_in[3];
  const float* rtab   = (const float*)d_in[4];
  const float* proj_w = (const float*)d_in[5];
  const float* proj_b = (const float*)d_in[6];
  const int*   ridx   = (const int*)d_in[7];
  float* out = (float*)d_out;

  char* p = (char*)d_ws;
  auto carve = [&](size_t bytes) { char* r = p; p += (bytes + 255) & ~(size_t)255; return r; };
  unsigned short* xb   = (unsigned short*)carve((size_t)ROWS * DIMC * 2);
  unsigned short* wb   = (unsigned short*)carve((size_t)3 * DIMC * DIMC * 2);
  unsigned short* pb   = (unsigned short*)carve((size_t)DIMC * DIMC * 2);
  float*          Bias = (float*)carve((size_t)NH * NTOK * NTOK * 4);
  unsigned short* Q    = (unsigned short*)carve((size_t)BHN * NTOK * HD * 2);
  unsigned short* Kb   = (unsigned short*)carve((size_t)BHN * NTOK * HD * 2);
  unsigned short* Vt   = (unsigned short*)carve((size_t)BHN * HD * NPAD * 2);
  unsigned short* Abuf = xb;  // xb is dead after GEMM1; attn fully overwrites

  k_cvt<<<(ROWS * DIMC / 4 + 255) / 256, 256, 0, stream>>>(x, xb, ROWS * DIMC / 4);
  k_cvt<<<(3 * DIMC * DIMC / 4 + 255) / 256, 256, 0, stream>>>(qkv_w, wb, 3 * DIMC * DIMC / 4);
  k_cvt<<<(DIMC * DIMC / 4 + 255) / 256, 256, 0, stream>>>(proj_w, pb, DIMC * DIMC / 4);
  k_bias<<<(NH * NTOK * NTOK + 255) / 256, 256, 0, stream>>>(rtab, ridx, Bias);
  k_vtpad<<<(BHN * HD * (NPAD - NTOK) + 255) / 256, 256, 0, stream>>>(Vt);

  k_gemm<0><<<1782, 256, 0, stream>>>(xb, wb, q_bias, v_bias, Q, Kb, Vt, nullptr);

  k_attn<<<BHN, 256, 0, stream>>>(Q, Kb, Vt, Bias, Abuf);

  k_gemm<1><<<594, 256, 0, stream>>>(Abuf, pb, proj_b, nullptr, nullptr, nullptr, nullptr, out);
}